// Round 6
// baseline (742.729 us; speedup 1.0000x reference)
//
#include <hip/hip_runtime.h>
#include <float.h>

// Problem constants (from reference file)
constexpr int C    = 512;          // DIM_CODES
constexpr int K    = 512;          // DICT_SIZE
constexpr int E    = 16;           // EMBED_DIM
constexpr int B    = 512;          // BATCH
constexpr int RB   = 256;          // batch rows per block (1 per lane)
constexpr int MUS  = C * E;        // 8192, mu row stride

// native vector type for nontemporal 16B stores
typedef float f32x4 __attribute__((ext_vector_type(4)));

// ============================================================================
// Kernel 1 — argmin scan. v6: dict delivered via the SCALAR pipe.
// v4/v5 post-mortem: scan is ~255us, LDS-broadcast-bound (4x ds_read_b128
// per k per wave; cost is per-instruction, ~12cyc, not per-unique-byte ->
// ~165us of LDS serialization vs ~36us VALU). The dict entry at iteration k
// is wave-UNIFORM -> load it with s_load_dwordx16 into SGPRs (readfirstlane
// forces uniformity; const __restrict__ + no stores in loop lets the backend
// prove no-clobber). v_fma_f32 reads the dict scalar directly as its one
// allowed SGPR operand -> zero LDS dict traffic, zero dict VGPRs.
// Numerics bit-identical to the verified v4/v5: same fma chains, same
// dist = fmaf(-2,acc,nm+nrm[k]), same sec<bd+1e-3 trigger, same wave-
// cooperative fp64 re-scan (dict from L2-hot global).
// ============================================================================
__launch_bounds__(256, 4)
__global__ void vq_scan(const float* __restrict__ mu,
                        const float* __restrict__ dict,
                        float* __restrict__ z,
                        float* __restrict__ zq,
                        int*   __restrict__ idx_t)
{
    const int c    = blockIdx.x;
    const int b0   = blockIdx.y * RB;
    const int tid  = threadIdx.x;
    const int lane = tid & 63;
    const int wave = tid >> 6;

    __shared__ float nrm_s[K];                      // 2 KB only

    const float* __restrict__ dbase = dict + (size_t)c * K * E;

    // ---- force the dict base into SGPRs (uniform across block): the
    // standard readfirstlane hoist so the k-loop loads select s_load.
    const float* dbu;
    {
        union { const float* p; int w[2]; } u;
        u.p = dbase;
        u.w[0] = __builtin_amdgcn_readfirstlane(u.w[0]);
        u.w[1] = __builtin_amdgcn_readfirstlane(u.w[1]);
        dbu = u.p;
    }

    // ---- per-code squared norms -> LDS (verified fma order)
#pragma unroll
    for (int rep = 0; rep < 2; ++rep) {
        const int k = tid + rep * 256;
        const float4* p = reinterpret_cast<const float4*>(dbase + k * E);
        const float4 d0 = p[0], d1 = p[1], d2 = p[2], d3 = p[3];
        float s = d0.x * d0.x;
        s = fmaf(d0.y, d0.y, s); s = fmaf(d0.z, d0.z, s); s = fmaf(d0.w, d0.w, s);
        s = fmaf(d1.x, d1.x, s); s = fmaf(d1.y, d1.y, s);
        s = fmaf(d1.z, d1.z, s); s = fmaf(d1.w, d1.w, s);
        s = fmaf(d2.x, d2.x, s); s = fmaf(d2.y, d2.y, s);
        s = fmaf(d2.z, d2.z, s); s = fmaf(d2.w, d2.w, s);
        s = fmaf(d3.x, d3.x, s); s = fmaf(d3.y, d3.y, s);
        s = fmaf(d3.z, d3.z, s); s = fmaf(d3.w, d3.w, s);
        nrm_s[k] = s;
    }
    __syncthreads();

    // ---- this lane's query row: 64B contiguous from global
    const int myrow = (wave << 6) + lane;
    const int b     = b0 + myrow;
    const float* __restrict__ mrow = mu + (size_t)b * MUS + c * E;
    float4 m0, m1, m2, m3;
    {
        const float4* p = reinterpret_cast<const float4*>(mrow);
        m0 = p[0]; m1 = p[1]; m2 = p[2]; m3 = p[3];
    }
    float nm = m0.x * m0.x;
    nm = fmaf(m0.y, m0.y, nm); nm = fmaf(m0.z, m0.z, nm); nm = fmaf(m0.w, m0.w, nm);
    nm = fmaf(m1.x, m1.x, nm); nm = fmaf(m1.y, m1.y, nm);
    nm = fmaf(m1.z, m1.z, nm); nm = fmaf(m1.w, m1.w, nm);
    nm = fmaf(m2.x, m2.x, nm); nm = fmaf(m2.y, m2.y, nm);
    nm = fmaf(m2.z, m2.z, nm); nm = fmaf(m2.w, m2.w, nm);
    nm = fmaf(m3.x, m3.x, nm); nm = fmaf(m3.y, m3.y, nm);
    nm = fmaf(m3.z, m3.z, nm); nm = fmaf(m3.w, m3.w, nm);

    // ---- serial scan over all K codes. Dict loads are uniform -> SMEM;
    // nrm is a cheap b32 LDS broadcast; everything else is VALU.
    float bd = FLT_MAX, sec = FLT_MAX;
    int   bk = K;
    const float4* __restrict__ du4 = reinterpret_cast<const float4*>(dbu);
#pragma unroll 4
    for (int k = 0; k < K; ++k) {
        const float4 d0 = du4[k * 4 + 0];
        const float4 d1 = du4[k * 4 + 1];
        const float4 d2 = du4[k * 4 + 2];
        const float4 d3 = du4[k * 4 + 3];
        const float  nr = nrm_s[k];
        float acc = d0.x * m0.x;
        acc = fmaf(d0.y, m0.y, acc); acc = fmaf(d0.z, m0.z, acc); acc = fmaf(d0.w, m0.w, acc);
        acc = fmaf(d1.x, m1.x, acc); acc = fmaf(d1.y, m1.y, acc);
        acc = fmaf(d1.z, m1.z, acc); acc = fmaf(d1.w, m1.w, acc);
        acc = fmaf(d2.x, m2.x, acc); acc = fmaf(d2.y, m2.y, acc);
        acc = fmaf(d2.z, m2.z, acc); acc = fmaf(d2.w, m2.w, acc);
        acc = fmaf(d3.x, m3.x, acc); acc = fmaf(d3.y, m3.y, acc);
        acc = fmaf(d3.z, m3.z, acc); acc = fmaf(d3.w, m3.w, acc);
        // identical rounding to the verified kernel
        const float dist = fmaf(-2.0f, acc, nm + nr);
        const bool  lt   = dist < bd;            // ascending k =>
        sec = lt ? bd : fminf(sec, dist);        // first-index ties
        bd  = lt ? dist : bd;
        bk  = lt ? k : bk;
    }

    // ---- rare near-tie path: wave-cooperative fp64 re-scan per flagged row.
    unsigned long long trig = __ballot(sec < bd + 1e-3f);
    while (trig) {
        const int r = __ffsll(trig) - 1;
        trig &= trig - 1;
        const int row = (wave << 6) + r;
        const float* __restrict__ qrow = mu + (size_t)(b0 + row) * MUS + c * E;

        double nmuD = 0.0;
#pragma unroll
        for (int t = 0; t < E; ++t) {
            const double mt = (double)qrow[t];
            nmuD += mt * mt;
        }
        double bD = DBL_MAX;
        int    bK = K;
#pragma unroll
        for (int i = 0; i < 8; ++i) {
            const int k = lane + 64 * i;
            const float* dk = dbase + (size_t)k * E;   // L2-hot global
            double nd = 0.0, dt = 0.0;
#pragma unroll
            for (int t = 0; t < 4; ++t) {
                const double dx = dk[4 * t + 0], dy = dk[4 * t + 1];
                const double dz = dk[4 * t + 2], dw = dk[4 * t + 3];
                const double mx = qrow[4 * t + 0], my = qrow[4 * t + 1];
                const double mz = qrow[4 * t + 2], mw = qrow[4 * t + 3];
                nd += dx * dx + dy * dy + dz * dz + dw * dw;
                dt += dx * mx + dy * my + dz * mz + dw * mw;
            }
            const double dist = nmuD + nd - 2.0 * dt;
            if (dist < bD) { bD = dist; bK = k; }
        }
#pragma unroll
        for (int off = 32; off; off >>= 1) {
            const double od = __shfl_down(bD, off);
            const int    ok = __shfl_down(bK, off);
            if (od < bD || (od == bD && ok < bK)) { bD = od; bK = ok; }
        }
        const int kwin = __shfl(bK, 0);
        if (lane == r) bk = kwin;
    }

    // ---- index out (transposed [c][b] => lanes write 256B coalesced)
    idx_t[c * B + b] = bk;

    // ---- z_embed and z = mu + (zq - mu), per-lane from registers.
    // fp32 op-for-op identical to the verified kernels.
    {
        const float4* dwin = reinterpret_cast<const float4*>(dbase + (size_t)bk * E);
        const float4 q0 = dwin[0], q1 = dwin[1], q2 = dwin[2], q3 = dwin[3];
        float* zqp = zq + (size_t)b * MUS + (size_t)c * E;
        float* zp  = z  + (size_t)b * MUS + (size_t)c * E;
        reinterpret_cast<float4*>(zqp)[0] = q0;
        reinterpret_cast<float4*>(zqp)[1] = q1;
        reinterpret_cast<float4*>(zqp)[2] = q2;
        reinterpret_cast<float4*>(zqp)[3] = q3;
        float4 z0, z1, z2, z3;
        z0.x = m0.x + (q0.x - m0.x); z0.y = m0.y + (q0.y - m0.y);
        z0.z = m0.z + (q0.z - m0.z); z0.w = m0.w + (q0.w - m0.w);
        z1.x = m1.x + (q1.x - m1.x); z1.y = m1.y + (q1.y - m1.y);
        z1.z = m1.z + (q1.z - m1.z); z1.w = m1.w + (q1.w - m1.w);
        z2.x = m2.x + (q2.x - m2.x); z2.y = m2.y + (q2.y - m2.y);
        z2.z = m2.z + (q2.z - m2.z); z2.w = m2.w + (q2.w - m2.w);
        z3.x = m3.x + (q3.x - m3.x); z3.y = m3.y + (q3.y - m3.y);
        z3.z = m3.z + (q3.z - m3.z); z3.w = m3.w + (q3.w - m3.w);
        reinterpret_cast<float4*>(zp)[0] = z0;
        reinterpret_cast<float4*>(zp)[1] = z1;
        reinterpret_cast<float4*>(zp)[2] = z2;
        reinterpret_cast<float4*>(zp)[3] = z3;
    }
}

// ============================================================================
// Kernel 2 — one-hot writer: perfectly linear grid-stride float4 nt-stores
// over the 512 MB oh buffer (fill-kernel pattern). Row index is wave-uniform
// -> readfirstlane + scalar idx lookup (idx_t is 1 MB, L2-hot).
// ============================================================================
__launch_bounds__(256)
__global__ void vq_onehot(const int* __restrict__ idx_t,
                          float* __restrict__ oh)
{
    const long TOT = (long)B * C * K / 4;            // 33,554,432 float4s
    const long stride = (long)gridDim.x * blockDim.x;
    long f4 = (long)blockIdx.x * blockDim.x + threadIdx.x;
#pragma unroll 4
    for (; f4 < TOT; f4 += stride) {
        const int rowu = __builtin_amdgcn_readfirstlane((int)(f4 >> 7));
        const int bb   = rowu >> 9;                  // / C
        const int cc   = rowu & (C - 1);
        const int kk   = idx_t[cc * B + bb];         // scalar load, L2-hot
        const int k0   = ((int)f4 & 127) << 2;
        f32x4 v;
        v.x = (k0 + 0 == kk) ? 1.0f : 0.0f;
        v.y = (k0 + 1 == kk) ? 1.0f : 0.0f;
        v.z = (k0 + 2 == kk) ? 1.0f : 0.0f;
        v.w = (k0 + 3 == kk) ? 1.0f : 0.0f;
        __builtin_nontemporal_store(v, reinterpret_cast<f32x4*>(oh) + f4);
    }
}

extern "C" void kernel_launch(void* const* d_in, const int* in_sizes, int n_in,
                              void* d_out, int out_size, void* d_ws, size_t ws_size,
                              hipStream_t stream)
{
    const float* mu   = (const float*)d_in[0];
    const float* dict = (const float*)d_in[1];

    float* z  = (float*)d_out;                 // (B, C*E)
    float* zq = z  + (size_t)B * C * E;        // (B, C*E)
    float* oh = zq + (size_t)B * C * E;        // (B, C, K)

    int* idx_t = (int*)d_ws;                   // C*B*4 = 1 MB workspace

    dim3 g1(C, B / RB);
    vq_scan<<<g1, 256, 0, stream>>>(mu, dict, z, zq, idx_t);
    vq_onehot<<<2048, 256, 0, stream>>>(idx_t, oh);
}

// Round 7
// 669.832 us; speedup vs baseline: 1.1088x; 1.1088x over previous
//
#include <hip/hip_runtime.h>
#include <float.h>

// Problem constants (from reference file)
constexpr int C    = 512;          // DIM_CODES
constexpr int K    = 512;          // DICT_SIZE
constexpr int E    = 16;           // EMBED_DIM
constexpr int B    = 512;          // BATCH
constexpr int MUS  = C * E;        // 8192, mu row stride
constexpr int R    = 4;            // query rows per lane

// native vector type for nontemporal 16B stores
typedef float f32x4 __attribute__((ext_vector_type(4)));

// ============================================================================
// Kernel 1 — argmin scan. v7: amortize dict LDS broadcasts over R=4 rows.
// v5 post-mortem: scan is LDS-INSTRUCTION-bound (4x ds_read_b128 per k per
// wave, ~12cyc each, cost per instruction not per byte => ~165us). v6's SMEM
// path regressed (s_load + ds_read share in-order-hostile lgkmcnt => full
// drains). Fix on the LDS path itself: each lane owns R=4 batch rows, so one
// dict broadcast per k feeds 4 fma chains. b128 count drops 4x (8.4M->2.1M
// device-wide => ~41us LDS), VALU ~36us/SIMD, overlapped => ~50-80us scan.
// Geometry: 128-thread blocks (2 waves), one block per c; lanes x slots =
// 128 x 4 = 512 = B. VGPR ~120, no spills.
// Numerics bit-identical to verified v4/v5: same fma chains, same
// dist = fmaf(-2,acc,nm+nrm[k]), same sec<bd+1e-3 trigger, same wave-
// cooperative fp64 re-scan per flagged row.
// ============================================================================
__launch_bounds__(128, 1)
__global__ void vq_scan(const float* __restrict__ mu,
                        const float* __restrict__ dict,
                        float* __restrict__ z,
                        float* __restrict__ zq,
                        int*   __restrict__ idx_t)
{
    const int c    = blockIdx.x;
    const int tid  = threadIdx.x;
    const int lane = tid & 63;
    const int wave = tid >> 6;

    __shared__ __align__(16) float dict_s[K * E];   // 32 KB
    __shared__ float nrm_s[K];                      // 2 KB

    const float* __restrict__ dbase = dict + (size_t)c * K * E;

    // ---- stage dict slice + per-code squared norms (verified fma order)
#pragma unroll
    for (int rep = 0; rep < 4; ++rep) {
        const int k = tid + rep * 128;
        const float4* p = reinterpret_cast<const float4*>(dbase + k * E);
        const float4 d0 = p[0], d1 = p[1], d2 = p[2], d3 = p[3];
        float s = d0.x * d0.x;
        s = fmaf(d0.y, d0.y, s); s = fmaf(d0.z, d0.z, s); s = fmaf(d0.w, d0.w, s);
        s = fmaf(d1.x, d1.x, s); s = fmaf(d1.y, d1.y, s);
        s = fmaf(d1.z, d1.z, s); s = fmaf(d1.w, d1.w, s);
        s = fmaf(d2.x, d2.x, s); s = fmaf(d2.y, d2.y, s);
        s = fmaf(d2.z, d2.z, s); s = fmaf(d2.w, d2.w, s);
        s = fmaf(d3.x, d3.x, s); s = fmaf(d3.y, d3.y, s);
        s = fmaf(d3.z, d3.z, s); s = fmaf(d3.w, d3.w, s);
        float4* q4 = reinterpret_cast<float4*>(&dict_s[k * E]);
        q4[0] = d0; q4[1] = d1; q4[2] = d2; q4[3] = d3;
        nrm_s[k] = s;
    }
    __syncthreads();

    // ---- this lane's R query rows: row = tid + 128*s  (covers B=512)
    float4 m[R][4];
    float  nm[R];
#pragma unroll
    for (int s = 0; s < R; ++s) {
        const int b = tid + 128 * s;
        const float4* p = reinterpret_cast<const float4*>(
            mu + (size_t)b * MUS + c * E);
        m[s][0] = p[0]; m[s][1] = p[1]; m[s][2] = p[2]; m[s][3] = p[3];
        float v = m[s][0].x * m[s][0].x;
        v = fmaf(m[s][0].y, m[s][0].y, v);
        v = fmaf(m[s][0].z, m[s][0].z, v);
        v = fmaf(m[s][0].w, m[s][0].w, v);
#pragma unroll
        for (int t = 1; t < 4; ++t) {
            v = fmaf(m[s][t].x, m[s][t].x, v);
            v = fmaf(m[s][t].y, m[s][t].y, v);
            v = fmaf(m[s][t].z, m[s][t].z, v);
            v = fmaf(m[s][t].w, m[s][t].w, v);
        }
        nm[s] = v;
    }

    // ---- serial scan over all K codes; ONE dict broadcast feeds R rows.
    float bd[R], sec[R];
    int   bk[R];
#pragma unroll
    for (int s = 0; s < R; ++s) { bd[s] = FLT_MAX; sec[s] = FLT_MAX; bk[s] = K; }

    const float4* __restrict__ ds4 = reinterpret_cast<const float4*>(dict_s);
#pragma unroll 4
    for (int k = 0; k < K; ++k) {
        const float4 d0 = ds4[k * 4 + 0];
        const float4 d1 = ds4[k * 4 + 1];
        const float4 d2 = ds4[k * 4 + 2];
        const float4 d3 = ds4[k * 4 + 3];
        const float  nr = nrm_s[k];
#pragma unroll
        for (int s = 0; s < R; ++s) {
            float acc = d0.x * m[s][0].x;
            acc = fmaf(d0.y, m[s][0].y, acc);
            acc = fmaf(d0.z, m[s][0].z, acc);
            acc = fmaf(d0.w, m[s][0].w, acc);
            acc = fmaf(d1.x, m[s][1].x, acc);
            acc = fmaf(d1.y, m[s][1].y, acc);
            acc = fmaf(d1.z, m[s][1].z, acc);
            acc = fmaf(d1.w, m[s][1].w, acc);
            acc = fmaf(d2.x, m[s][2].x, acc);
            acc = fmaf(d2.y, m[s][2].y, acc);
            acc = fmaf(d2.z, m[s][2].z, acc);
            acc = fmaf(d2.w, m[s][2].w, acc);
            acc = fmaf(d3.x, m[s][3].x, acc);
            acc = fmaf(d3.y, m[s][3].y, acc);
            acc = fmaf(d3.z, m[s][3].z, acc);
            acc = fmaf(d3.w, m[s][3].w, acc);
            // identical rounding to the verified kernel
            const float dist = fmaf(-2.0f, acc, nm[s] + nr);
            const bool  lt   = dist < bd[s];         // ascending k =>
            sec[s] = lt ? bd[s] : fminf(sec[s], dist);  // first-index ties
            bd[s]  = lt ? dist : bd[s];
            bk[s]  = lt ? k : bk[s];
        }
    }

    // ---- rare near-tie path: wave-cooperative fp64 re-scan per flagged row.
#pragma unroll
    for (int s = 0; s < R; ++s) {
        unsigned long long trig = __ballot(sec[s] < bd[s] + 1e-3f);
        while (trig) {
            const int r = __ffsll(trig) - 1;
            trig &= trig - 1;
            const int row = (wave << 6) + r + 128 * s;
            const float* __restrict__ qrow = mu + (size_t)row * MUS + c * E;

            double nmuD = 0.0;
#pragma unroll
            for (int t = 0; t < E; ++t) {
                const double mt = (double)qrow[t];
                nmuD += mt * mt;
            }
            double bD = DBL_MAX;
            int    bK = K;
#pragma unroll
            for (int i = 0; i < 8; ++i) {
                const int kk = lane + 64 * i;
                const float* dk = &dict_s[kk * E];
                double nd = 0.0, dt = 0.0;
#pragma unroll
                for (int t = 0; t < 4; ++t) {
                    const double dx = dk[4 * t + 0], dy = dk[4 * t + 1];
                    const double dz = dk[4 * t + 2], dw = dk[4 * t + 3];
                    const double mx = qrow[4 * t + 0], my = qrow[4 * t + 1];
                    const double mz = qrow[4 * t + 2], mw = qrow[4 * t + 3];
                    nd += dx * dx + dy * dy + dz * dz + dw * dw;
                    dt += dx * mx + dy * my + dz * mz + dw * mw;
                }
                const double dist = nmuD + nd - 2.0 * dt;
                if (dist < bD) { bD = dist; bK = kk; }
            }
#pragma unroll
            for (int off = 32; off; off >>= 1) {
                const double od = __shfl_down(bD, off);
                const int    ok = __shfl_down(bK, off);
                if (od < bD || (od == bD && ok < bK)) { bD = od; bK = ok; }
            }
            const int kwin = __shfl(bK, 0);
            if (lane == r) bk[s] = kwin;
        }
    }

    // ---- outputs per slot: idx (coalesced), z/zq from registers.
#pragma unroll
    for (int s = 0; s < R; ++s) {
        const int b = tid + 128 * s;
        idx_t[c * B + b] = bk[s];

        const float4* dwin = reinterpret_cast<const float4*>(&dict_s[bk[s] * E]);
        const float4 q0 = dwin[0], q1 = dwin[1], q2 = dwin[2], q3 = dwin[3];
        float* zqp = zq + (size_t)b * MUS + (size_t)c * E;
        float* zp  = z  + (size_t)b * MUS + (size_t)c * E;
        reinterpret_cast<float4*>(zqp)[0] = q0;
        reinterpret_cast<float4*>(zqp)[1] = q1;
        reinterpret_cast<float4*>(zqp)[2] = q2;
        reinterpret_cast<float4*>(zqp)[3] = q3;
        float4 z0, z1, z2, z3;
        z0.x = m[s][0].x + (q0.x - m[s][0].x); z0.y = m[s][0].y + (q0.y - m[s][0].y);
        z0.z = m[s][0].z + (q0.z - m[s][0].z); z0.w = m[s][0].w + (q0.w - m[s][0].w);
        z1.x = m[s][1].x + (q1.x - m[s][1].x); z1.y = m[s][1].y + (q1.y - m[s][1].y);
        z1.z = m[s][1].z + (q1.z - m[s][1].z); z1.w = m[s][1].w + (q1.w - m[s][1].w);
        z2.x = m[s][2].x + (q2.x - m[s][2].x); z2.y = m[s][2].y + (q2.y - m[s][2].y);
        z2.z = m[s][2].z + (q2.z - m[s][2].z); z2.w = m[s][2].w + (q2.w - m[s][2].w);
        z3.x = m[s][3].x + (q3.x - m[s][3].x); z3.y = m[s][3].y + (q3.y - m[s][3].y);
        z3.z = m[s][3].z + (q3.z - m[s][3].z); z3.w = m[s][3].w + (q3.w - m[s][3].w);
        reinterpret_cast<float4*>(zp)[0] = z0;
        reinterpret_cast<float4*>(zp)[1] = z1;
        reinterpret_cast<float4*>(zp)[2] = z2;
        reinterpret_cast<float4*>(zp)[3] = z3;
    }
}

// ============================================================================
// Kernel 2 — one-hot writer: perfectly linear grid-stride float4 nt-stores
// over the 512 MB oh buffer (fill-kernel pattern, ~6.25 TB/s). Row index is
// wave-uniform -> readfirstlane + scalar idx lookup (idx_t is 1 MB, L2-hot).
// ============================================================================
__launch_bounds__(256)
__global__ void vq_onehot(const int* __restrict__ idx_t,
                          float* __restrict__ oh)
{
    const long TOT = (long)B * C * K / 4;            // 33,554,432 float4s
    const long stride = (long)gridDim.x * blockDim.x;
    long f4 = (long)blockIdx.x * blockDim.x + threadIdx.x;
#pragma unroll 4
    for (; f4 < TOT; f4 += stride) {
        const int rowu = __builtin_amdgcn_readfirstlane((int)(f4 >> 7));
        const int bb   = rowu >> 9;                  // / C
        const int cc   = rowu & (C - 1);
        const int kk   = idx_t[cc * B + bb];         // scalar load, L2-hot
        const int k0   = ((int)f4 & 127) << 2;
        f32x4 v;
        v.x = (k0 + 0 == kk) ? 1.0f : 0.0f;
        v.y = (k0 + 1 == kk) ? 1.0f : 0.0f;
        v.z = (k0 + 2 == kk) ? 1.0f : 0.0f;
        v.w = (k0 + 3 == kk) ? 1.0f : 0.0f;
        __builtin_nontemporal_store(v, reinterpret_cast<f32x4*>(oh) + f4);
    }
}

extern "C" void kernel_launch(void* const* d_in, const int* in_sizes, int n_in,
                              void* d_out, int out_size, void* d_ws, size_t ws_size,
                              hipStream_t stream)
{
    const float* mu   = (const float*)d_in[0];
    const float* dict = (const float*)d_in[1];

    float* z  = (float*)d_out;                 // (B, C*E)
    float* zq = z  + (size_t)B * C * E;        // (B, C*E)
    float* oh = zq + (size_t)B * C * E;        // (B, C, K)

    int* idx_t = (int*)d_ws;                   // C*B*4 = 1 MB workspace

    vq_scan<<<dim3(C), 128, 0, stream>>>(mu, dict, z, zq, idx_t);
    vq_onehot<<<2048, 256, 0, stream>>>(idx_t, oh);
}